// Round 7
// baseline (276.310 us; speedup 1.0000x reference)
//
#include <hip/hip_runtime.h>
#include <math.h>

#define N_PIX 65536
#define EPSF 1e-6f
#define CHUNKS 32
#define PX_PER_CHUNK 2048   // 65536 / 32
#define PX_PER_WAVE 512     // 4 waves per block, 8 super-tiles of 64 px
#define N_TILES (PX_PER_WAVE / 64)
#define N_JOBS 48           // 2 imgs * 8 batch * 3 channels

typedef __attribute__((ext_vector_type(2))) float f2;
using short8 = __attribute__((ext_vector_type(8))) short;
using f32x4  = __attribute__((ext_vector_type(4))) float;

__device__ __forceinline__ float rcp_fast(float x) { return __builtin_amdgcn_rcpf(x); }

// round-half-up bf16 pack: {lo=a, hi=b}. All inputs are positive finite, so
// +0x8000 then truncate is correct round-half-up (bias <= 1/2 ulp vs RNE).
__device__ __forceinline__ uint32_t pk_bf16_rhu(float a, float b) {
    const uint32_t ua = __builtin_bit_cast(uint32_t, a) + 0x8000u;
    const uint32_t ub = __builtin_bit_cast(uint32_t, b) + 0x8000u;
    return __builtin_amdgcn_perm(ub, ua, 0x07060302u);
}

// phase A: pixel -> (u*50, v*50, weight)
__device__ __forceinline__ float4 phaseA(float pr, float pg, float pb, int c) {
    const float r  = pr + EPSF;
    const float g  = pg + EPSF;
    const float bl = pb + EPSF;
    const float wgt = sqrtf(fmaf(r, r, fmaf(g, g, bl * bl)));
    const float lr = __logf(r), lg = __logf(g), lb2 = __logf(bl);
    // channel c: u = l_c - l_a, v = l_c - l_b;  c0:(a,b)=(g,b) c1:(r,b) c2:(r,g)
    const float l0 = (c == 0) ? lr : ((c == 1) ? lg : lb2);
    const float lu = (c == 0) ? lg : lr;
    const float lv = (c == 2) ? lg : lb2;
    return make_float4((l0 - lu) * 50.0f, (l0 - lv) * 50.0f, wgt, 0.0f);
}

// ---------------------------------------------------------------------------
// Kernel 1: per (job, chunk) partial 64x64 histogram via bf16 MFMA with
// fragment-direct operand generation. 256 thr/block x 1536 blocks = 6 blk/CU.
// NO global atomics (R6 post-mortem: 6.3M device-scope atomics = ~50 us
// funnel at the coherence point) — plain coalesced partial stores + separate
// reduce kernel. Per wave: double-buffered 2x288-float LDS uvw buffer; tile
// st+1's phase A is computed and written BEFORE phase B of tile st, hiding
// the ds_write->ds_read round-trip. Phase B: each lane evaluates exactly the
// RBF values its MFMA fragments need (A[m=l15][k=quad*8+j], 4 m-tiles) via
// broadcast ds_read_b128 (quad stride 144B -> conflict-free, verified R5) +
// rcp-of-product; 16 MFMA per K=32 half.
// ---------------------------------------------------------------------------
__global__ __launch_bounds__(256, 4) void hist_kernel(
    const float* __restrict__ x, const float* __restrict__ y,
    float* __restrict__ partial)
{
    const int blk = blockIdx.x;            // 0..1535
    const int chunk = blk & (CHUNKS - 1);
    const int job = blk / CHUNKS;          // 0..47
    const int c = job % 3;
    const int ib = job / 3;                // img*8 + b
    const int img = ib >> 3;
    const int b = ib & 7;
    const float* __restrict__ src = (img == 0 ? x : y) + (size_t)b * 3 * N_PIX;

    __shared__ __align__(16) float lds[4096];   // 16 KB: 4 waves x 2 x 288 / reduce
    const int tid = threadIdx.x;
    const int lane = tid & 63;
    const int wv = tid >> 6;
    float* __restrict__ wbuf = lds + wv * 576;  // double-buffered uvw

    const int quad = lane >> 4;
    const int l15 = lane & 15;
    // negated scaled centers for this lane's 4 m-rows: -(c_m * 50), m = mt*16+l15
    f2 ncb01, ncb23;
    {
        const float c0 = (-3.0f + (float)(l15)      * (6.0f / 63.0f)) * 50.0f;
        const float c1 = (-3.0f + (float)(16 + l15) * (6.0f / 63.0f)) * 50.0f;
        const float c2 = (-3.0f + (float)(32 + l15) * (6.0f / 63.0f)) * 50.0f;
        const float c3 = (-3.0f + (float)(48 + l15) * (6.0f / 63.0f)) * 50.0f;
        ncb01 = (f2){-c0, -c1};
        ncb23 = (f2){-c2, -c3};
    }
    const f2 one2 = {1.0f, 1.0f};

    f32x4 acc[16];                         // acc[mt*4+nt]
#pragma unroll
    for (int i = 0; i < 16; ++i) acc[i] = (f32x4){0.f, 0.f, 0.f, 0.f};

    const int px0 = chunk * PX_PER_CHUNK + wv * PX_PER_WAVE;

    // ---- pipeline prologue: tile 0 phase A; prefetch tile 1 raw ----
    {
        const int n = px0 + lane;
        const float4 uvw = phaseA(src[n], src[N_PIX + n], src[2 * N_PIX + n], c);
        *(float4*)(wbuf + lane * 4 + (lane >> 3) * 4) = uvw;
    }
    float pr = 0.f, pg = 0.f, pb = 0.f;
    {
        const int n = px0 + 64 + lane;
        pr = src[n]; pg = src[N_PIX + n]; pb = src[2 * N_PIX + n];
    }

#pragma unroll
    for (int st = 0; st < N_TILES; ++st) {
        const int cur = st & 1;

        // ---- stage tile st+1: phase A from prefetched regs, write other buf,
        //      then issue prefetch of tile st+2 ----
        if (st + 1 < N_TILES) {
            const float4 uvw = phaseA(pr, pg, pb, c);
            float* nb = wbuf + (1 - cur) * 288;
            *(float4*)(nb + lane * 4 + (lane >> 3) * 4) = uvw;
            if (st + 2 < N_TILES) {
                const int n2 = px0 + (st + 2) * 64 + lane;
                pr = src[n2]; pg = src[N_PIX + n2]; pb = src[2 * N_PIX + n2];
            }
        }

        // ---- phase B on tile st's buffer ----
        const float* __restrict__ cb = wbuf + cur * 288;
#pragma unroll
        for (int h = 0; h < 2; ++h) {              // two K=32 halves
            const int base = h * 32 + quad * 8;    // first pixel this lane consumes
            const float4* __restrict__ pbase =
                (const float4*)(cb + base * 4 + (base >> 3) * 4);
            int aU[4][4], aV[4][4];                // fragment words [mt][jp]

#pragma unroll
            for (int jp = 0; jp < 4; ++jp) {       // j = 2jp (even), 2jp+1 (odd)
                const float4 pe = pbase[2 * jp];
                const float4 po = pbase[2 * jp + 1];

                float aue[4], auo[4], bve[4], bvo[4];
#pragma unroll
                for (int eo = 0; eo < 2; ++eo) {
                    const float ru = eo ? po.x : pe.x;
                    const float rv = eo ? po.y : pe.y;
                    const float rw = eo ? po.z : pe.z;
                    float* au = eo ? auo : aue;
                    float* bv = eo ? bvo : bve;

                    const f2 ruu = {ru, ru};
                    const f2 tu01 = ruu + ncb01;
                    const f2 tu23 = ruu + ncb23;
                    const f2 qu01 = __builtin_elementwise_fma(tu01, tu01, one2);
                    const f2 qu23 = __builtin_elementwise_fma(tu23, tu23, one2);
                    // rcp of product: 1 rcp serves 2 denominators (err ~3 ulp fp32)
                    const float Ru0 = rcp_fast(qu01.x * qu01.y) * rw;
                    const float Ru1 = rcp_fast(qu23.x * qu23.y) * rw;
                    au[0] = Ru0 * qu01.y; au[1] = Ru0 * qu01.x;
                    au[2] = Ru1 * qu23.y; au[3] = Ru1 * qu23.x;

                    const f2 rvv = {rv, rv};
                    const f2 tv01 = rvv + ncb01;
                    const f2 tv23 = rvv + ncb23;
                    const f2 qv01 = __builtin_elementwise_fma(tv01, tv01, one2);
                    const f2 qv23 = __builtin_elementwise_fma(tv23, tv23, one2);
                    const float Rv0 = rcp_fast(qv01.x * qv01.y);
                    const float Rv1 = rcp_fast(qv23.x * qv23.y);
                    bv[0] = Rv0 * qv01.y; bv[1] = Rv0 * qv01.x;
                    bv[2] = Rv1 * qv23.y; bv[3] = Rv1 * qv23.x;
                }
#pragma unroll
                for (int mt = 0; mt < 4; ++mt) {
                    aU[mt][jp] = pk_bf16_rhu(aue[mt], auo[mt]);
                    aV[mt][jp] = pk_bf16_rhu(bve[mt], bvo[mt]);
                }
            }

            short8 af[4], bf[4];
#pragma unroll
            for (int mt = 0; mt < 4; ++mt) {
                af[mt] = __builtin_bit_cast(short8,
                    make_int4(aU[mt][0], aU[mt][1], aU[mt][2], aU[mt][3]));
                bf[mt] = __builtin_bit_cast(short8,
                    make_int4(aV[mt][0], aV[mt][1], aV[mt][2], aV[mt][3]));
            }
#pragma unroll
            for (int mt = 0; mt < 4; ++mt)
#pragma unroll
                for (int nt = 0; nt < 4; ++nt)
                    acc[mt * 4 + nt] = __builtin_amdgcn_mfma_f32_16x16x32_bf16(
                        af[mt], bf[nt], acc[mt * 4 + nt], 0, 0, 0);
        }
    }

    // ---- Block-reduce the 4 waves in LDS, then plain coalesced stores ----
    __syncthreads();
    for (int i = tid; i < 4096; i += 256) lds[i] = 0.0f;
    __syncthreads();
#pragma unroll
    for (int mt = 0; mt < 4; ++mt)
#pragma unroll
        for (int nt = 0; nt < 4; ++nt)
#pragma unroll
            for (int i = 0; i < 4; ++i) {
                const int m = mt * 16 + quad * 4 + i;   // C/D: row = quad*4+reg
                const int nn = nt * 16 + l15;           //      col = lane&15
                atomicAdd(&lds[m * 64 + nn], acc[mt * 4 + nt][i]);
            }
    __syncthreads();

    float* __restrict__ outp = partial + (size_t)blk * 4096;
    for (int i = tid; i < 4096; i += 256) outp[i] = lds[i];
}

// ---------------------------------------------------------------------------
// Kernel 2: sum the 32 chunk-partials of each job -> hist[48][4096]
// ---------------------------------------------------------------------------
__global__ __launch_bounds__(256) void reduce_partials_kernel(
    const float* __restrict__ partial, float* __restrict__ hist)
{
    const int job = blockIdx.x >> 4;                       // 0..47
    const int e = ((blockIdx.x & 15) << 8) | threadIdx.x;  // 0..4095
    const float* p = partial + (size_t)job * CHUNKS * 4096 + e;
    float s = 0.0f;
#pragma unroll
    for (int k = 0; k < CHUNKS; ++k) s += p[(size_t)k * 4096];
    hist[(size_t)job * 4096 + e] = s;
}

// ---------------------------------------------------------------------------
// Kernel 3: per-batch normalization + Hellinger distance; each block adds its
// batch's sqrt(0.5*h)/8 into out[0] (out zeroed by memset beforehand).
// ---------------------------------------------------------------------------
__global__ __launch_bounds__(1024) void loss_kernel(
    const float* __restrict__ hist, float* __restrict__ out)
{
    const int b = blockIdx.x;  // 0..7
    __shared__ float red[16];
    const int tid = threadIdx.x;
    const int wv = tid >> 6;
    const float* xh = hist + (size_t)(b * 3) * 4096;        // img 0, batch b
    const float* yh = hist + (size_t)((8 + b) * 3) * 4096;  // img 1, batch b

    float sx = 0.0f, sy = 0.0f;
    for (int i = tid; i < 3 * 4096; i += 1024) { sx += xh[i]; sy += yh[i]; }
    float v = sx;
#pragma unroll
    for (int o = 32; o > 0; o >>= 1) v += __shfl_down(v, o, 64);
    if ((tid & 63) == 0) red[wv] = v;
    __syncthreads();
    float tx = 0.0f;
#pragma unroll
    for (int i = 0; i < 16; ++i) tx += red[i];
    __syncthreads();
    v = sy;
#pragma unroll
    for (int o = 32; o > 0; o >>= 1) v += __shfl_down(v, o, 64);
    if ((tid & 63) == 0) red[wv] = v;
    __syncthreads();
    float ty = 0.0f;
#pragma unroll
    for (int i = 0; i < 16; ++i) ty += red[i];
    __syncthreads();

    const float invx = 1.0f / tx, invy = 1.0f / ty;
    float h = 0.0f;
    for (int i = tid; i < 3 * 4096; i += 1024) {
        const float d = sqrtf(yh[i] * invy) - sqrtf(xh[i] * invx);
        h = fmaf(d, d, h);
    }
#pragma unroll
    for (int o = 32; o > 0; o >>= 1) h += __shfl_down(h, o, 64);
    if ((tid & 63) == 0) red[wv] = h;
    __syncthreads();
    if (tid == 0) {
        float hs = 0.0f;
#pragma unroll
        for (int i = 0; i < 16; ++i) hs += red[i];
        atomicAdd(out, sqrtf(0.5f * hs) * 0.125f);
    }
}

extern "C" void kernel_launch(void* const* d_in, const int* in_sizes, int n_in,
                              void* d_out, int out_size, void* d_ws, size_t ws_size,
                              hipStream_t stream)
{
    const float* x = (const float*)d_in[0];
    const float* y = (const float*)d_in[1];
    float* ws = (float*)d_ws;
    float* partial = ws;                                  // 1536*4096 floats (25.2 MB)
    float* hist = ws + (size_t)N_JOBS * CHUNKS * 4096;    // 48*4096 floats
    float* outf = (float*)d_out;

    hipMemsetAsync(outf, 0, sizeof(float), stream);
    hipLaunchKernelGGL(hist_kernel, dim3(N_JOBS * CHUNKS), dim3(256), 0, stream,
                       x, y, partial);
    hipLaunchKernelGGL(reduce_partials_kernel, dim3(N_JOBS * 16), dim3(256), 0, stream,
                       partial, hist);
    hipLaunchKernelGGL(loss_kernel, dim3(8), dim3(1024), 0, stream, hist, outf);
}

// Round 8
// 272.868 us; speedup vs baseline: 1.0126x; 1.0126x over previous
//
#include <hip/hip_runtime.h>
#include <math.h>

#define N_PIX 65536
#define EPSF 1e-6f
#define CHUNKS 32
#define PX_PER_CHUNK 2048   // 65536 / 32
#define PX_PER_WAVE 512     // 4 waves per block, 8 super-tiles of 64 px
#define N_TILES (PX_PER_WAVE / 64)
#define N_JOBS 48           // 2 imgs * 8 batch * 3 channels

typedef __attribute__((ext_vector_type(2))) float f2;
using short8 = __attribute__((ext_vector_type(8))) short;
using f32x4  = __attribute__((ext_vector_type(4))) float;

__device__ __forceinline__ float rcp_fast(float x) { return __builtin_amdgcn_rcpf(x); }

#if __has_builtin(__builtin_amdgcn_cvt_pk_bf16_f32)
// gfx950 HW pack: 1 instruction, RNE
typedef __attribute__((ext_vector_type(2))) __bf16 bf16x2_t;
__device__ __forceinline__ uint32_t pk_bf16(float a, float b) {
    return __builtin_bit_cast(uint32_t, __builtin_amdgcn_cvt_pk_bf16_f32(a, b));
}
#else
// fallback: round-half-up (inputs positive finite), 3 ops
__device__ __forceinline__ uint32_t pk_bf16(float a, float b) {
    const uint32_t ua = __builtin_bit_cast(uint32_t, a) + 0x8000u;
    const uint32_t ub = __builtin_bit_cast(uint32_t, b) + 0x8000u;
    return __builtin_amdgcn_perm(ub, ua, 0x07060302u);
}
#endif

// phase A: pixel -> (u*50, v*50, weight)
__device__ __forceinline__ float4 phaseA(float pr, float pg, float pb, int c) {
    const float r  = pr + EPSF;
    const float g  = pg + EPSF;
    const float bl = pb + EPSF;
    const float wgt = sqrtf(fmaf(r, r, fmaf(g, g, bl * bl)));
    const float lr = __logf(r), lg = __logf(g), lb2 = __logf(bl);
    // channel c: u = l_c - l_a, v = l_c - l_b;  c0:(a,b)=(g,b) c1:(r,b) c2:(r,g)
    const float l0 = (c == 0) ? lr : ((c == 1) ? lg : lb2);
    const float lu = (c == 0) ? lg : lr;
    const float lv = (c == 2) ? lg : lb2;
    return make_float4((l0 - lu) * 50.0f, (l0 - lv) * 50.0f, wgt, 0.0f);
}

// ---------------------------------------------------------------------------
// Kernel 1: per (job, chunk) partial 64x64 histogram via bf16 MFMA with
// fragment-direct operand generation. 256 thr/block x 1536 blocks.
// R8: ROLLED super-tile loop (R6/R7's fully-unrolled ~45KB body thrashed the
// I$: VALUBusy fell when waves rose), 1-instr v_cvt_pk_bf16_f32 pack, single
// staging buffer + register prefetch (R7's double-buffer pipeline spilled:
// +35MB scratch writes). No global atomics (R6: 6.3M device atomics drain).
// Per wave: phase A computes (u*50,v*50,w) per pixel (lane=pixel) into a
// private padded 1.125KB LDS buffer (quad read stride 144B -> conflict-free,
// verified R5: SQ_LDS_BANK_CONFLICT=0); phase B evaluates exactly the RBF
// values this lane's MFMA fragments need (A[m=l15][k=quad*8+j], 4 m-tiles)
// via broadcast ds_read_b128 + rcp-of-product; 16 MFMA per K=32 half.
// Epilogue: 4-wave LDS reduce, plain coalesced partial stores.
// ---------------------------------------------------------------------------
__global__ __launch_bounds__(256, 4) void hist_kernel(
    const float* __restrict__ x, const float* __restrict__ y,
    float* __restrict__ partial)
{
    const int blk = blockIdx.x;            // 0..1535
    const int chunk = blk & (CHUNKS - 1);
    const int job = blk / CHUNKS;          // 0..47
    const int c = job % 3;
    const int ib = job / 3;                // img*8 + b
    const int img = ib >> 3;
    const int b = ib & 7;
    const float* __restrict__ src = (img == 0 ? x : y) + (size_t)b * 3 * N_PIX;

    __shared__ __align__(16) float lds[4096];   // 16 KB: 4 x 288-float wbufs / reduce
    const int tid = threadIdx.x;
    const int lane = tid & 63;
    const int wv = tid >> 6;
    float* __restrict__ wbuf = lds + wv * 288;  // 64 px * float4, +16B pad per 8 px

    const int quad = lane >> 4;
    const int l15 = lane & 15;
    // negated scaled centers for this lane's 4 m-rows: -(c_m * 50), m = mt*16+l15
    f2 ncb01, ncb23;
    {
        const float c0 = (-3.0f + (float)(l15)      * (6.0f / 63.0f)) * 50.0f;
        const float c1 = (-3.0f + (float)(16 + l15) * (6.0f / 63.0f)) * 50.0f;
        const float c2 = (-3.0f + (float)(32 + l15) * (6.0f / 63.0f)) * 50.0f;
        const float c3 = (-3.0f + (float)(48 + l15) * (6.0f / 63.0f)) * 50.0f;
        ncb01 = (f2){-c0, -c1};
        ncb23 = (f2){-c2, -c3};
    }
    const f2 one2 = {1.0f, 1.0f};

    f32x4 acc[16];                         // acc[mt*4+nt]
#pragma unroll
    for (int i = 0; i < 16; ++i) acc[i] = (f32x4){0.f, 0.f, 0.f, 0.f};

    const int px0 = chunk * PX_PER_CHUNK + wv * PX_PER_WAVE;

    // prefetch super-tile 0
    float pr, pg, pb;
    {
        const int n = px0 + lane;
        pr = src[n]; pg = src[N_PIX + n]; pb = src[2 * N_PIX + n];
    }

#pragma unroll 1
    for (int st = 0; st < N_TILES; ++st) {
        // ---- Phase A: one pixel per lane; stage to LDS (same-wave, in-order) ----
        const float4 uvw = phaseA(pr, pg, pb, c);
        *(float4*)(wbuf + lane * 4 + (lane >> 3) * 4) = uvw;

        if (st + 1 < N_TILES) {            // prefetch next tile's raw pixels
            const int n2 = px0 + (st + 1) * 64 + lane;
            pr = src[n2]; pg = src[N_PIX + n2]; pb = src[2 * N_PIX + n2];
        }

#pragma unroll
        for (int h = 0; h < 2; ++h) {              // two K=32 halves
            const int base = h * 32 + quad * 8;    // first pixel this lane consumes
            const float4* __restrict__ pbase =
                (const float4*)(wbuf + base * 4 + (base >> 3) * 4);
            int aU[4][4], aV[4][4];                // fragment words [mt][jp]

#pragma unroll
            for (int jp = 0; jp < 4; ++jp) {       // j = 2jp (even), 2jp+1 (odd)
                const float4 pe = pbase[2 * jp];
                const float4 po = pbase[2 * jp + 1];

                float aue[4], auo[4], bve[4], bvo[4];
#pragma unroll
                for (int eo = 0; eo < 2; ++eo) {
                    const float ru = eo ? po.x : pe.x;
                    const float rv = eo ? po.y : pe.y;
                    const float rw = eo ? po.z : pe.z;
                    float* au = eo ? auo : aue;
                    float* bv = eo ? bvo : bve;

                    const f2 ruu = {ru, ru};
                    const f2 tu01 = ruu + ncb01;
                    const f2 tu23 = ruu + ncb23;
                    const f2 qu01 = __builtin_elementwise_fma(tu01, tu01, one2);
                    const f2 qu23 = __builtin_elementwise_fma(tu23, tu23, one2);
                    // rcp of product: 1 rcp serves 2 denominators (err ~3 ulp fp32)
                    const float Ru0 = rcp_fast(qu01.x * qu01.y) * rw;
                    const float Ru1 = rcp_fast(qu23.x * qu23.y) * rw;
                    au[0] = Ru0 * qu01.y; au[1] = Ru0 * qu01.x;
                    au[2] = Ru1 * qu23.y; au[3] = Ru1 * qu23.x;

                    const f2 rvv = {rv, rv};
                    const f2 tv01 = rvv + ncb01;
                    const f2 tv23 = rvv + ncb23;
                    const f2 qv01 = __builtin_elementwise_fma(tv01, tv01, one2);
                    const f2 qv23 = __builtin_elementwise_fma(tv23, tv23, one2);
                    const float Rv0 = rcp_fast(qv01.x * qv01.y);
                    const float Rv1 = rcp_fast(qv23.x * qv23.y);
                    bv[0] = Rv0 * qv01.y; bv[1] = Rv0 * qv01.x;
                    bv[2] = Rv1 * qv23.y; bv[3] = Rv1 * qv23.x;
                }
#pragma unroll
                for (int mt = 0; mt < 4; ++mt) {
                    aU[mt][jp] = pk_bf16(aue[mt], auo[mt]);
                    aV[mt][jp] = pk_bf16(bve[mt], bvo[mt]);
                }
            }

            short8 af[4], bf[4];
#pragma unroll
            for (int mt = 0; mt < 4; ++mt) {
                af[mt] = __builtin_bit_cast(short8,
                    make_int4(aU[mt][0], aU[mt][1], aU[mt][2], aU[mt][3]));
                bf[mt] = __builtin_bit_cast(short8,
                    make_int4(aV[mt][0], aV[mt][1], aV[mt][2], aV[mt][3]));
            }
#pragma unroll
            for (int mt = 0; mt < 4; ++mt)
#pragma unroll
                for (int nt = 0; nt < 4; ++nt)
                    acc[mt * 4 + nt] = __builtin_amdgcn_mfma_f32_16x16x32_bf16(
                        af[mt], bf[nt], acc[mt * 4 + nt], 0, 0, 0);
        }
    }

    // ---- Block-reduce the 4 waves in LDS, then plain coalesced stores ----
    __syncthreads();
    for (int i = tid; i < 4096; i += 256) lds[i] = 0.0f;
    __syncthreads();
#pragma unroll
    for (int mt = 0; mt < 4; ++mt)
#pragma unroll
        for (int nt = 0; nt < 4; ++nt)
#pragma unroll
            for (int i = 0; i < 4; ++i) {
                const int m = mt * 16 + quad * 4 + i;   // C/D: row = quad*4+reg
                const int nn = nt * 16 + l15;           //      col = lane&15
                atomicAdd(&lds[m * 64 + nn], acc[mt * 4 + nt][i]);
            }
    __syncthreads();

    float* __restrict__ outp = partial + (size_t)blk * 4096;
    for (int i = tid; i < 4096; i += 256) outp[i] = lds[i];
}

// ---------------------------------------------------------------------------
// Kernel 2: sum the 32 chunk-partials of each job -> hist[48][4096]
// ---------------------------------------------------------------------------
__global__ __launch_bounds__(256) void reduce_partials_kernel(
    const float* __restrict__ partial, float* __restrict__ hist)
{
    const int job = blockIdx.x >> 4;                       // 0..47
    const int e = ((blockIdx.x & 15) << 8) | threadIdx.x;  // 0..4095
    const float* p = partial + (size_t)job * CHUNKS * 4096 + e;
    float s = 0.0f;
#pragma unroll
    for (int k = 0; k < CHUNKS; ++k) s += p[(size_t)k * 4096];
    hist[(size_t)job * 4096 + e] = s;
}

// ---------------------------------------------------------------------------
// Kernel 3: per-batch normalization + Hellinger distance; each block adds its
// batch's sqrt(0.5*h)/8 into out[0] (out zeroed by memset beforehand).
// ---------------------------------------------------------------------------
__global__ __launch_bounds__(1024) void loss_kernel(
    const float* __restrict__ hist, float* __restrict__ out)
{
    const int b = blockIdx.x;  // 0..7
    __shared__ float red[16];
    const int tid = threadIdx.x;
    const int wv = tid >> 6;
    const float* xh = hist + (size_t)(b * 3) * 4096;        // img 0, batch b
    const float* yh = hist + (size_t)((8 + b) * 3) * 4096;  // img 1, batch b

    float sx = 0.0f, sy = 0.0f;
    for (int i = tid; i < 3 * 4096; i += 1024) { sx += xh[i]; sy += yh[i]; }
    float v = sx;
#pragma unroll
    for (int o = 32; o > 0; o >>= 1) v += __shfl_down(v, o, 64);
    if ((tid & 63) == 0) red[wv] = v;
    __syncthreads();
    float tx = 0.0f;
#pragma unroll
    for (int i = 0; i < 16; ++i) tx += red[i];
    __syncthreads();
    v = sy;
#pragma unroll
    for (int o = 32; o > 0; o >>= 1) v += __shfl_down(v, o, 64);
    if ((tid & 63) == 0) red[wv] = v;
    __syncthreads();
    float ty = 0.0f;
#pragma unroll
    for (int i = 0; i < 16; ++i) ty += red[i];
    __syncthreads();

    const float invx = 1.0f / tx, invy = 1.0f / ty;
    float h = 0.0f;
    for (int i = tid; i < 3 * 4096; i += 1024) {
        const float d = sqrtf(yh[i] * invy) - sqrtf(xh[i] * invx);
        h = fmaf(d, d, h);
    }
#pragma unroll
    for (int o = 32; o > 0; o >>= 1) h += __shfl_down(h, o, 64);
    if ((tid & 63) == 0) red[wv] = h;
    __syncthreads();
    if (tid == 0) {
        float hs = 0.0f;
#pragma unroll
        for (int i = 0; i < 16; ++i) hs += red[i];
        atomicAdd(out, sqrtf(0.5f * hs) * 0.125f);
    }
}

extern "C" void kernel_launch(void* const* d_in, const int* in_sizes, int n_in,
                              void* d_out, int out_size, void* d_ws, size_t ws_size,
                              hipStream_t stream)
{
    const float* x = (const float*)d_in[0];
    const float* y = (const float*)d_in[1];
    float* ws = (float*)d_ws;
    float* partial = ws;                                  // 1536*4096 floats (25.2 MB)
    float* hist = ws + (size_t)N_JOBS * CHUNKS * 4096;    // 48*4096 floats
    float* outf = (float*)d_out;

    hipMemsetAsync(outf, 0, sizeof(float), stream);
    hipLaunchKernelGGL(hist_kernel, dim3(N_JOBS * CHUNKS), dim3(256), 0, stream,
                       x, y, partial);
    hipLaunchKernelGGL(reduce_partials_kernel, dim3(N_JOBS * 16), dim3(256), 0, stream,
                       partial, hist);
    hipLaunchKernelGGL(loss_kernel, dim3(8), dim3(1024), 0, stream, hist, outf);
}

// Round 9
// 175.000 us; speedup vs baseline: 1.5789x; 1.5592x over previous
//
#include <hip/hip_runtime.h>
#include <math.h>

#define N_PIX 65536
#define EPSF 1e-6f
#define CHUNKS 16
#define PX_PER_CHUNK 4096   // 65536 / 16
#define PX_PER_WAVE 1024    // 4 waves per block, 16 super-tiles of 64 px
#define N_TILES (PX_PER_WAVE / 64)
#define N_JOBS 48           // 2 imgs * 8 batch * 3 channels
#define LN2_50 34.65735903f // 50 * ln(2): log2 -> scaled-ln

typedef __attribute__((ext_vector_type(2))) float f2;
using short8 = __attribute__((ext_vector_type(8))) short;
using f32x4  = __attribute__((ext_vector_type(4))) float;

__device__ __forceinline__ float rcp_fast(float x) { return __builtin_amdgcn_rcpf(x); }

#if __has_builtin(__builtin_amdgcn_cvt_pk_bf16_f32)
typedef __attribute__((ext_vector_type(2))) __bf16 bf16x2_t;
__device__ __forceinline__ uint32_t pk_bf16(float a, float b) {
    return __builtin_bit_cast(uint32_t, __builtin_amdgcn_cvt_pk_bf16_f32(a, b));
}
#else
// fallback: round-half-up (inputs positive finite), 3 ops
__device__ __forceinline__ uint32_t pk_bf16(float a, float b) {
    const uint32_t ua = __builtin_bit_cast(uint32_t, a) + 0x8000u;
    const uint32_t ub = __builtin_bit_cast(uint32_t, b) + 0x8000u;
    return __builtin_amdgcn_perm(ub, ua, 0x07060302u);
}
#endif

// phase A: pixel -> (u*50, v*50, weight); log2-based (ln2 folded into scale)
__device__ __forceinline__ float4 phaseA(float pr, float pg, float pb, int c) {
    const float r  = pr + EPSF;
    const float g  = pg + EPSF;
    const float bl = pb + EPSF;
    const float wgt = sqrtf(fmaf(r, r, fmaf(g, g, bl * bl)));
    const float lr = __log2f(r), lg = __log2f(g), lb2 = __log2f(bl);
    // channel c: u = l_c - l_a, v = l_c - l_b;  c0:(a,b)=(g,b) c1:(r,b) c2:(r,g)
    const float l0 = (c == 0) ? lr : ((c == 1) ? lg : lb2);
    const float lu = (c == 0) ? lg : lr;
    const float lv = (c == 2) ? lg : lb2;
    return make_float4((l0 - lu) * LN2_50, (l0 - lv) * LN2_50, wgt, 0.0f);
}

// ---------------------------------------------------------------------------
// Kernel 1: per (job, chunk) partial 64x64 histogram via bf16 MFMA with
// fragment-direct operand generation. 256 thr/block x 768 blocks (R8 post-
// mortem: duration tracked block count — per-block epilogue overhead — while
// VALU-busy time was invariant; fewer, bigger blocks win).
// Epilogue is ATOMIC-FREE: 4 chunks (one per mt); each wave b128-writes its
// 4 nt acc tiles to a wave strip at linear addresses, then all 256 threads
// read 4 linear b128 (conflict-free) + sum + store to the partial directly.
// Main loop: phase A computes (u*50,v*50,w) per pixel (lane=pixel) into a
// private padded LDS buffer (quad read stride 144B -> conflict-free, R5);
// phase B evaluates exactly the RBF values this lane's fragments need
// (A[m=l15][k=quad*8+j], 4 m-tiles) via broadcast ds_read_b128 +
// rcp-of-4-product (1 v_rcp per 4 denominators); 16 MFMA per K=32 half.
// ---------------------------------------------------------------------------
__global__ __launch_bounds__(256, 4) void hist_kernel(
    const float* __restrict__ x, const float* __restrict__ y,
    float* __restrict__ partial)
{
    const int blk = blockIdx.x;            // 0..767
    const int chunk = blk & (CHUNKS - 1);
    const int job = blk / CHUNKS;          // 0..47
    const int c = job % 3;
    const int ib = job / 3;                // img*8 + b
    const int img = ib >> 3;
    const int b = ib & 7;
    const float* __restrict__ src = (img == 0 ? x : y) + (size_t)b * 3 * N_PIX;

    __shared__ __align__(16) float lds[4096];   // 16 KB: wbufs / epilogue strips
    const int tid = threadIdx.x;
    const int lane = tid & 63;
    const int wv = tid >> 6;
    float* __restrict__ wbuf = lds + wv * 288;  // 64 px * float4, +16B pad per 8 px

    const int quad = lane >> 4;
    const int l15 = lane & 15;
    // negated scaled centers for this lane's 4 m-rows: -(c_m * 50), m = mt*16+l15
    f2 ncb01, ncb23;
    {
        const float c0 = (-3.0f + (float)(l15)      * (6.0f / 63.0f)) * 50.0f;
        const float c1 = (-3.0f + (float)(16 + l15) * (6.0f / 63.0f)) * 50.0f;
        const float c2 = (-3.0f + (float)(32 + l15) * (6.0f / 63.0f)) * 50.0f;
        const float c3 = (-3.0f + (float)(48 + l15) * (6.0f / 63.0f)) * 50.0f;
        ncb01 = (f2){-c0, -c1};
        ncb23 = (f2){-c2, -c3};
    }
    const f2 one2 = {1.0f, 1.0f};

    f32x4 acc[16];                         // acc[mt*4+nt]
#pragma unroll
    for (int i = 0; i < 16; ++i) acc[i] = (f32x4){0.f, 0.f, 0.f, 0.f};

    const int px0 = chunk * PX_PER_CHUNK + wv * PX_PER_WAVE;

    // prefetch super-tile 0
    float pr, pg, pb;
    {
        const int n = px0 + lane;
        pr = src[n]; pg = src[N_PIX + n]; pb = src[2 * N_PIX + n];
    }

#pragma unroll 1
    for (int st = 0; st < N_TILES; ++st) {
        // ---- Phase A: one pixel per lane; stage to LDS (same-wave, in-order) ----
        const float4 uvw = phaseA(pr, pg, pb, c);
        *(float4*)(wbuf + lane * 4 + (lane >> 3) * 4) = uvw;

        if (st + 1 < N_TILES) {            // prefetch next tile's raw pixels
            const int n2 = px0 + (st + 1) * 64 + lane;
            pr = src[n2]; pg = src[N_PIX + n2]; pb = src[2 * N_PIX + n2];
        }

#pragma unroll
        for (int h = 0; h < 2; ++h) {              // two K=32 halves
            const int base = h * 32 + quad * 8;    // first pixel this lane consumes
            const float4* __restrict__ pbase =
                (const float4*)(wbuf + base * 4 + (base >> 3) * 4);
            int aU[4][4], aV[4][4];                // fragment words [mt][jp]

#pragma unroll
            for (int jp = 0; jp < 4; ++jp) {       // j = 2jp (even), 2jp+1 (odd)
                const float4 pe = pbase[2 * jp];
                const float4 po = pbase[2 * jp + 1];

                float aue[4], auo[4], bve[4], bvo[4];
#pragma unroll
                for (int eo = 0; eo < 2; ++eo) {
                    const float ru = eo ? po.x : pe.x;
                    const float rv = eo ? po.y : pe.y;
                    const float rw = eo ? po.z : pe.z;
                    float* au = eo ? auo : aue;
                    float* bv = eo ? bvo : bve;

                    const f2 ruu = {ru, ru};
                    const f2 tu01 = ruu + ncb01;
                    const f2 tu23 = ruu + ncb23;
                    const f2 qu01 = __builtin_elementwise_fma(tu01, tu01, one2);
                    const f2 qu23 = __builtin_elementwise_fma(tu23, tu23, one2);
                    // one rcp serves 4 denominators (max product ~6.5e19, fp32-safe)
                    const float pu01 = qu01.x * qu01.y;
                    const float pu23 = qu23.x * qu23.y;
                    const float Ru = rcp_fast(pu01 * pu23) * rw;   // fold w
                    const float ru01 = Ru * pu23, ru23 = Ru * pu01;
                    au[0] = ru01 * qu01.y; au[1] = ru01 * qu01.x;
                    au[2] = ru23 * qu23.y; au[3] = ru23 * qu23.x;

                    const f2 rvv = {rv, rv};
                    const f2 tv01 = rvv + ncb01;
                    const f2 tv23 = rvv + ncb23;
                    const f2 qv01 = __builtin_elementwise_fma(tv01, tv01, one2);
                    const f2 qv23 = __builtin_elementwise_fma(tv23, tv23, one2);
                    const float pv01 = qv01.x * qv01.y;
                    const float pv23 = qv23.x * qv23.y;
                    const float Rv = rcp_fast(pv01 * pv23);
                    const float rv01 = Rv * pv23, rv23 = Rv * pv01;
                    bv[0] = rv01 * qv01.y; bv[1] = rv01 * qv01.x;
                    bv[2] = rv23 * qv23.y; bv[3] = rv23 * qv23.x;
                }
#pragma unroll
                for (int mt = 0; mt < 4; ++mt) {
                    aU[mt][jp] = pk_bf16(aue[mt], auo[mt]);
                    aV[mt][jp] = pk_bf16(bve[mt], bvo[mt]);
                }
            }

            short8 af[4], bf[4];
#pragma unroll
            for (int mt = 0; mt < 4; ++mt) {
                af[mt] = __builtin_bit_cast(short8,
                    make_int4(aU[mt][0], aU[mt][1], aU[mt][2], aU[mt][3]));
                bf[mt] = __builtin_bit_cast(short8,
                    make_int4(aV[mt][0], aV[mt][1], aV[mt][2], aV[mt][3]));
            }
#pragma unroll
            for (int mt = 0; mt < 4; ++mt)
#pragma unroll
                for (int nt = 0; nt < 4; ++nt)
                    acc[mt * 4 + nt] = __builtin_amdgcn_mfma_f32_16x16x32_bf16(
                        af[mt], bf[nt], acc[mt * 4 + nt], 0, 0, 0);
        }
    }

    // ---- Atomic-free epilogue: 4 chunks over mt; linear b128 traffic only ----
    float* __restrict__ outp = partial + (size_t)blk * 4096;
#pragma unroll 1
    for (int ch = 0; ch < 4; ++ch) {
        __syncthreads();                   // previous chunk (or main loop) done
#pragma unroll
        for (int nt = 0; nt < 4; ++nt)     // wave strip: [wv][nt*256 + lane*4 + i]
            *(f32x4*)(lds + wv * 1024 + nt * 256 + lane * 4) = acc[ch * 4 + nt];
        __syncthreads();
        const int e4 = tid * 4;            // 0..1023, linear -> conflict-free b128
        const f32x4 s0 = *(const f32x4*)(lds +        e4);
        const f32x4 s1 = *(const f32x4*)(lds + 1024 + e4);
        const f32x4 s2 = *(const f32x4*)(lds + 2048 + e4);
        const f32x4 s3 = *(const f32x4*)(lds + 3072 + e4);
        const f32x4 s = (s0 + s1) + (s2 + s3);
        // e4 = nt*256 + l*4;  m = ch*16 + (l>>4)*4 + i;  n = nt*16 + (l&15)
        const int l = tid & 63;
        const int n = ((tid >> 6) << 4) | (l & 15);
        float* op = outp + (ch * 16 + (l >> 4) * 4) * 64 + n;
        op[0] = s.x; op[64] = s.y; op[128] = s.z; op[192] = s.w;
    }
}

// ---------------------------------------------------------------------------
// Kernel 2: sum the 16 chunk-partials of each job -> hist[48][4096], and
// accumulate per-(img,batch) totals (block reduce + 1 atomic per block).
// ---------------------------------------------------------------------------
__global__ __launch_bounds__(256) void reduce_partials_kernel(
    const float* __restrict__ partial, float* __restrict__ hist,
    float* __restrict__ totals)
{
    const int job = blockIdx.x >> 4;                       // 0..47
    const int e = ((blockIdx.x & 15) << 8) | threadIdx.x;  // 0..4095
    const float* p = partial + (size_t)job * CHUNKS * 4096 + e;
    float s = 0.0f;
#pragma unroll
    for (int k = 0; k < CHUNKS; ++k) s += p[(size_t)k * 4096];
    hist[(size_t)job * 4096 + e] = s;

    __shared__ float red[4];
    float v = s;
#pragma unroll
    for (int o = 32; o > 0; o >>= 1) v += __shfl_down(v, o, 64);
    if ((threadIdx.x & 63) == 0) red[threadIdx.x >> 6] = v;
    __syncthreads();
    if (threadIdx.x == 0)
        atomicAdd(&totals[job / 3], red[0] + red[1] + red[2] + red[3]);
}

// ---------------------------------------------------------------------------
// Kernel 3: Hellinger distance per batch (totals precomputed); adds
// sqrt(0.5*h)/8 into out[0] (out zeroed by memset beforehand).
// ---------------------------------------------------------------------------
__global__ __launch_bounds__(1024) void loss_kernel(
    const float* __restrict__ hist, const float* __restrict__ totals,
    float* __restrict__ out)
{
    const int b = blockIdx.x;  // 0..7
    __shared__ float red[16];
    const int tid = threadIdx.x;
    const float* xh = hist + (size_t)(b * 3) * 4096;        // img 0, batch b
    const float* yh = hist + (size_t)((8 + b) * 3) * 4096;  // img 1, batch b
    const float invx = 1.0f / totals[b];
    const float invy = 1.0f / totals[8 + b];

    float h = 0.0f;
    for (int i = tid; i < 3 * 4096; i += 1024) {
        const float d = sqrtf(yh[i] * invy) - sqrtf(xh[i] * invx);
        h = fmaf(d, d, h);
    }
#pragma unroll
    for (int o = 32; o > 0; o >>= 1) h += __shfl_down(h, o, 64);
    if ((tid & 63) == 0) red[tid >> 6] = h;
    __syncthreads();
    if (tid == 0) {
        float hs = 0.0f;
#pragma unroll
        for (int i = 0; i < 16; ++i) hs += red[i];
        atomicAdd(out, sqrtf(0.5f * hs) * 0.125f);
    }
}

extern "C" void kernel_launch(void* const* d_in, const int* in_sizes, int n_in,
                              void* d_out, int out_size, void* d_ws, size_t ws_size,
                              hipStream_t stream)
{
    const float* x = (const float*)d_in[0];
    const float* y = (const float*)d_in[1];
    float* ws = (float*)d_ws;
    float* partial = ws;                                  // 768*4096 floats (12.6 MB)
    float* hist = ws + (size_t)N_JOBS * CHUNKS * 4096;    // 48*4096 floats
    float* totals = hist + (size_t)N_JOBS * 4096;         // 16 floats
    float* outf = (float*)d_out;

    hipMemsetAsync(totals, 0, 16 * sizeof(float), stream);
    hipMemsetAsync(outf, 0, sizeof(float), stream);
    hipLaunchKernelGGL(hist_kernel, dim3(N_JOBS * CHUNKS), dim3(256), 0, stream,
                       x, y, partial);
    hipLaunchKernelGGL(reduce_partials_kernel, dim3(N_JOBS * 16), dim3(256), 0, stream,
                       partial, hist, totals);
    hipLaunchKernelGGL(loss_kernel, dim3(8), dim3(1024), 0, stream, hist, totals, outf);
}